// Round 2
// baseline (966.029 us; speedup 1.0000x reference)
//
#include <hip/hip_runtime.h>
#include <math.h>

#define NN 128
#define SM 129   // padded LDS stride for 128-wide f32 tiles
#define TS 132   // k3 tile stride (16B-aligned rows -> float4 LDS loads)
#define RS 132   // row-panel stride (doubles)
#define SS 17    // per-wave scratch stride (doubles)
#define SD 130   // padded LDS stride (doubles) for f64 matrix staging
#define EP 132   // emb-partial stride (floats)

typedef double d4 __attribute__((ext_vector_type(4)));

// ---------------------------------------------------------------------------
// K1 (R17): build symmetric-normalized Laplacian per graph (f32) only.
// ---------------------------------------------------------------------------
__global__ __launch_bounds__(256) void k1_lap(
    const int* __restrict__ src, const int* __restrict__ dst,
    int E, float* __restrict__ Lout) {
  extern __shared__ float sm1[];            // A[128*129] + dinv[128]
  float* A    = sm1;
  float* dinv = sm1 + NN * SM;
  const int g   = blockIdx.x;
  const int tid = threadIdx.x;

  for (int e = tid; e < NN * NN; e += 256) {
    int i = e >> 7, j = e & 127;
    A[i * SM + j] = 0.f;
  }
  __syncthreads();
  const int* s = src + (size_t)g * E;
  const int* d = dst + (size_t)g * E;
  for (int e = tid; e < E; e += 256) {
    int a = s[e], b = d[e];
    A[a * SM + b] = 1.f;     // benign races: all write 1.0
    A[b * SM + a] = 1.f;
  }
  __syncthreads();
  if (tid < NN) {
    float acc = 0.f;
    for (int j = 0; j < NN; ++j) acc += A[tid * SM + j];
    dinv[tid] = (acc > 0.f) ? (float)(1.0 / sqrt((double)acc)) : 0.f;
  }
  __syncthreads();
  float* Lg = Lout + (size_t)g * NN * NN;
  for (int e = tid; e < NN * NN; e += 256) {
    int i = e >> 7, j = e & 127;
    Lg[e] = ((i == j) ? 1.f : 0.f) - dinv[i] * dinv[j] * A[i * SM + j];
  }
}

// ---------------------------------------------------------------------------
// KPOW2 (R17): L2 = L @ L, 256 blocks (g = bid>>2, quarter q = bid&3 =
// 32-row band). B = L staged f64 in LDS; wave w: 16-row band q*32+16*(w&1),
// cb pair 2*(w>>1). Full-machine version of the old half-idle kernel.
// ---------------------------------------------------------------------------
__global__ __launch_bounds__(512, 1) void kpow2(
    const float* __restrict__ L, double* __restrict__ L2) {
  extern __shared__ double Bs[];            // 128 x 130 f64
  const int bid = blockIdx.x;
  const int g = bid >> 2, q = bid & 3;
  const int tid = threadIdx.x;
  const int wv = tid >> 6, ln = tid & 63;
  const int m  = ln & 15, kq = ln >> 4;
  const int rb = 32 * q + 16 * (wv & 1);    // row-band base
  const int cb0 = 2 * (wv >> 1);            // 2 col tiles

  int rIdx[4], cIdx[4];
  {
    d4 z = {0.0, 0.0, 0.0, 0.0};
    d4 pr = __builtin_amdgcn_mfma_f64_16x16x4f64((double)m, 1.0, z, 0, 0, 0);
    d4 pc = __builtin_amdgcn_mfma_f64_16x16x4f64(1.0, (double)m, z, 0, 0, 0);
#pragma unroll
    for (int r = 0; r < 4; ++r) {
      rIdx[r] = ((int)(pr[r] * 0.25 + 0.5)) & 15;
      cIdx[r] = ((int)(pc[r] * 0.25 + 0.5)) & 15;
    }
  }

  const float* Lg = L + (size_t)g * NN * NN;
  for (int e = tid; e < NN * NN; e += 512) {
    int i = e >> 7, j = e & 127;
    Bs[i * SD + j] = (double)Lg[e];
  }
  __syncthreads();

  d4 acc[2];
#pragma unroll
  for (int c = 0; c < 2; ++c) {
    acc[c][0] = 0.0; acc[c][1] = 0.0; acc[c][2] = 0.0; acc[c][3] = 0.0;
  }
  for (int kc = 0; kc < 32; ++kc) {
    double a = Bs[(rb + m) * SD + 4 * kc + kq];
#pragma unroll
    for (int c = 0; c < 2; ++c) {
      double b = Bs[(4 * kc + kq) * SD + 16 * (cb0 + c) + m];
      acc[c] = __builtin_amdgcn_mfma_f64_16x16x4f64(a, b, acc[c], 0, 0, 0);
    }
  }
  double* out = L2 + (size_t)g * NN * NN;
#pragma unroll
  for (int c = 0; c < 2; ++c)
#pragma unroll
    for (int r = 0; r < 4; ++r)
      out[(rb + rIdx[r]) * NN + 16 * (cb0 + c) + cIdx[r]] = acc[c][r];
}

// ---------------------------------------------------------------------------
// KPOW34 (R17): 256 blocks = g(6b) x half(1b) x job(1b).
// job 0: L3 = L2 @ L ; job 1: L4 = L2 @ L2. Each block: 64-row half-band.
// Wave w: band 64h + 16*(w&3), cb quad 4*(w>>2). B staged f64 in LDS;
// A rows read from global L2 (L2/L3-cached).
// ---------------------------------------------------------------------------
__global__ __launch_bounds__(512, 1) void kpow34(
    const float* __restrict__ L, const double* __restrict__ L2,
    double* __restrict__ L3, double* __restrict__ L4) {
  extern __shared__ double Bs[];            // 128 x 130 f64
  const int bid = blockIdx.x;
  const int g = bid >> 2, h = (bid >> 1) & 1, job = bid & 1;
  const int tid = threadIdx.x;
  const int wv = tid >> 6, ln = tid & 63;
  const int m  = ln & 15, kq = ln >> 4;
  const int rb = 64 * h + 16 * (wv & 3);
  const int cb0 = 4 * (wv >> 2);

  int rIdx[4], cIdx[4];
  {
    d4 z = {0.0, 0.0, 0.0, 0.0};
    d4 pr = __builtin_amdgcn_mfma_f64_16x16x4f64((double)m, 1.0, z, 0, 0, 0);
    d4 pc = __builtin_amdgcn_mfma_f64_16x16x4f64(1.0, (double)m, z, 0, 0, 0);
#pragma unroll
    for (int r = 0; r < 4; ++r) {
      rIdx[r] = ((int)(pr[r] * 0.25 + 0.5)) & 15;
      cIdx[r] = ((int)(pc[r] * 0.25 + 0.5)) & 15;
    }
  }

  const float*  Lg  = L  + (size_t)g * NN * NN;
  const double* L2g = L2 + (size_t)g * NN * NN;
  if (job == 0) {
    for (int e = tid; e < NN * NN; e += 512) {
      int i = e >> 7, j = e & 127;
      Bs[i * SD + j] = (double)Lg[e];
    }
  } else {
    for (int e = tid; e < NN * NN; e += 512) {
      int i = e >> 7, j = e & 127;
      Bs[i * SD + j] = L2g[e];
    }
  }
  __syncthreads();

  d4 acc[4];
#pragma unroll
  for (int c = 0; c < 4; ++c) {
    acc[c][0] = 0.0; acc[c][1] = 0.0; acc[c][2] = 0.0; acc[c][3] = 0.0;
  }
  for (int kc = 0; kc < 32; ++kc) {
    double a = L2g[(rb + m) * NN + 4 * kc + kq];
#pragma unroll
    for (int c = 0; c < 4; ++c) {
      double b = Bs[(4 * kc + kq) * SD + 16 * (cb0 + c) + m];
      acc[c] = __builtin_amdgcn_mfma_f64_16x16x4f64(a, b, acc[c], 0, 0, 0);
    }
  }
  double* out = (job == 0 ? L3 : L4) + (size_t)g * NN * NN;
#pragma unroll
  for (int c = 0; c < 4; ++c)
#pragma unroll
    for (int r = 0; r < 4; ++r)
      out[(rb + rIdx[r]) * NN + 16 * (cb0 + c) + cIdx[r]] = acc[c][r];
}

// ---------------------------------------------------------------------------
// 16x16 in-wave Gauss-Jordan inverse on sr[4] (sr[r] = M[4r+kq][m]).
// ---------------------------------------------------------------------------
__device__ __forceinline__ void gj16(double sr[4], int m, int kq) {
#pragma unroll
  for (int k = 0; k < 16; ++k) {
    const int kr = k >> 2, kl = k & 3;
    double pv   = __shfl(sr[kr], 16 * kl + k);
    double rowv = __shfl(sr[kr], 16 * kl + m);
    double cv[4];
#pragma unroll
    for (int r = 0; r < 4; ++r) cv[r] = __shfl(sr[r], 16 * kq + k);
    double dp = 1.0 / pv;
#pragma unroll
    for (int r = 0; r < 4; ++r) {
      int i = 4 * r + kq;
      double nv;
      if (i == k)      nv = (m == k) ? dp : rowv * dp;
      else if (m == k) nv = -cv[r] * dp;
      else             nv = fma(-(cv[r] * dp), rowv, sr[r]);
      sr[r] = nv;
    }
  }
}

// ---------------------------------------------------------------------------
// K2 (R19): R14 structure with ONE barrier per GJ step (was 3).
// Panel staging + pivot inverse are merged into a single pivot-wave region
// (same-wave LDS write->read needs no block barrier), and Rp/Pv are
// double-buffered so the end-of-step barrier is unnecessary. Per-wave code
// and live ranges match R14 (one gj16 instantiation) to avoid the R18
// scratch-spill regression.
// ---------------------------------------------------------------------------
__global__ __launch_bounds__(512, 4) void k2_filter(
    const float* __restrict__ L, const double* __restrict__ L2,
    const double* __restrict__ L3, const double* __restrict__ L4,
    const float* __restrict__ C, int NF, float* __restrict__ W) {
  extern __shared__ char smraw[];
  double* Rp0 = (double*)smraw;                  // 16 x 132
  double* Rp1 = Rp0 + 16 * RS;                   // 16 x 132
  double* Scd = Rp1 + 16 * RS;                   // 8 wave scratches 16x17
  double* Pv0 = Scd + 8 * 16 * SS;               // Pi double buffer 16x17
  double* Pv1 = Pv0 + 16 * SS;

  const int bid = blockIdx.x;
  const int g = bid / NF, f = bid % NF;
  const int tid = threadIdx.x;
  const int wv = tid >> 6, ln = tid & 63;
  const int m  = ln & 15, kq = ln >> 4;
  double* S = Scd + wv * 16 * SS;

  double csum = 0.0;
  for (int q = 0; q < NF; ++q) { double c = (double)C[q]; csum += c * c; }
  double cn = sqrt(csum); if (cn < 1e-12) cn = 1e-12;
  const double a4 = 6.25e-6;                     // (STEP/2)^4
  const double coef = 1.4142135623730951 * a4 * ((double)C[f] / cn);
  const float  bf = (float)((double)f * 0.1);
  const double bb = (double)bf;
  const double c3 = -4.0 * bb;
  const double c2 = 6.0 * bb * bb;
  const double c1 = -4.0 * bb * bb * bb;
  const double c0 = bb * bb * bb * bb + a4;

  int rIdx[4], cIdx[4];
  {
    d4 z = {0.0, 0.0, 0.0, 0.0};
    d4 pr = __builtin_amdgcn_mfma_f64_16x16x4f64((double)m, 1.0, z, 0, 0, 0);
    d4 pc = __builtin_amdgcn_mfma_f64_16x16x4f64(1.0, (double)m, z, 0, 0, 0);
#pragma unroll
    for (int r = 0; r < 4; ++r) {
      rIdx[r] = ((int)(pr[r] * 0.25 + 0.5)) & 15;
      cIdx[r] = ((int)(pc[r] * 0.25 + 0.5)) & 15;
    }
  }

  // phase A: assemble T (D-layout) from the power matrices -- pure n^2
  const float*  Lg  = L  + (size_t)g * NN * NN;
  const double* L2g = L2 + (size_t)g * NN * NN;
  const double* L3g = L3 + (size_t)g * NN * NN;
  const double* L4g = L4 + (size_t)g * NN * NN;
  d4 T[8];
#pragma unroll
  for (int cb = 0; cb < 8; ++cb)
#pragma unroll
    for (int r = 0; r < 4; ++r) {
      int i = 16 * wv + rIdx[r], j = 16 * cb + cIdx[r];
      int idx = i * NN + j;
      double v = L4g[idx];
      v = fma(c3, L3g[idx], v);
      v = fma(c2, L2g[idx], v);
      v = fma(c1, (double)Lg[idx], v);
      if (i == j) v += c0;
      T[cb][r] = v;
    }

  // blocked GJ: ONE block barrier per step. Buffer b = t&1; readers of
  // buffer b at step t finish before barrier(t+1); the next writer of
  // buffer b (wave t+2, step t+2) starts after barrier(t+1). Safe.
#pragma unroll 1
  for (int t = 0; t < 8; ++t) {
    double* Rc = (t & 1) ? Rp1 : Rp0;
    double* Pc = (t & 1) ? Pv1 : Pv0;

    // pivot wave: stage panel, then pivot-inverse from its own writes
    if (wv == t) {
#pragma unroll
      for (int cb = 0; cb < 8; ++cb)
#pragma unroll
        for (int r = 0; r < 4; ++r)
          Rc[rIdx[r] * RS + 16 * cb + cIdx[r]] = T[cb][r];
      __builtin_amdgcn_wave_barrier();
      double sr[4];
#pragma unroll
      for (int r = 0; r < 4; ++r) sr[r] = Rc[(4 * r + kq) * RS + 16 * t + m];
      gj16(sr, m, kq);
#pragma unroll
      for (int r = 0; r < 4; ++r) Pc[(4 * r + kq) * SS + m] = sr[r];
    }
    __syncthreads();                               // the ONLY barrier

    // fold Pi_t into column block t
    if (wv == t) {
#pragma unroll
      for (int r = 0; r < 4; ++r) T[t][r] = Pc[rIdx[r] * SS + cIdx[r]];
    } else {
#pragma unroll
      for (int r = 0; r < 4; ++r) S[rIdx[r] * SS + cIdx[r]] = T[t][r];
      __builtin_amdgcn_wave_barrier();
      d4 ncv = {0.0, 0.0, 0.0, 0.0};
#pragma unroll
      for (int kc = 0; kc < 4; ++kc) {
        double a = S[m * SS + 4 * kc + kq];
        double b = -Pc[(4 * kc + kq) * SS + m];
        ncv = __builtin_amdgcn_mfma_f64_16x16x4f64(a, b, ncv, 0, 0, 0);
      }
      T[t] = ncv;
      __builtin_amdgcn_wave_barrier();
#pragma unroll
      for (int r = 0; r < 4; ++r) S[rIdx[r] * SS + cIdx[r]] = T[t][r];
      __builtin_amdgcn_wave_barrier();
    }

    // bulk update of all other column blocks
    const double* asrc = (wv == t) ? Pc : S;
#pragma unroll
    for (int cb = 0; cb < 8; ++cb) {
      if (cb == t) continue;
      d4 acc;
      if (wv == t) { acc[0] = 0.0; acc[1] = 0.0; acc[2] = 0.0; acc[3] = 0.0; }
      else         { acc = T[cb]; }
#pragma unroll
      for (int kc = 0; kc < 4; ++kc) {
        double a = asrc[m * SS + 4 * kc + kq];
        double b = Rc[(4 * kc + kq) * RS + 16 * cb + m];
        acc = __builtin_amdgcn_mfma_f64_16x16x4f64(a, b, acc, 0, 0, 0);
      }
      T[cb] = acc;
    }
    // no end barrier: next step uses the other Rp/Pv buffer
  }

  // phase 5: W += coef * K^{-1}
  float* Wg = W + (size_t)g * NN * NN;
#pragma unroll
  for (int cb = 0; cb < 8; ++cb)
#pragma unroll
    for (int r = 0; r < 4; ++r)
      atomicAdd(&Wg[(16 * wv + rIdx[r]) * NN + 16 * cb + cIdx[r]],
                (float)(coef * T[cb][r]));
}

// ---------------------------------------------------------------------------
// K3 (R16, unchanged): fp32 VALU fused kernel, stride-132 float4 LDS loads.
// ---------------------------------------------------------------------------
__global__ __launch_bounds__(512, 1) void k3_fused(
    const float* __restrict__ x, const float* __restrict__ rs,
    const float* __restrict__ W, float* __restrict__ G,
    float* __restrict__ emb, int F0, int R, int DTOT, int NCH,
    float rscale) {
  extern __shared__ float sm3[];
  float* ldsW = sm3;                 // 128*132, later yT
  float* ldsX = sm3 + NN * TS;       // 128*132, later emb partials (32x132)
  const int bid = blockIdx.x;
  const int g = bid / NCH;
  const int c = bid % NCH;
  const int d0 = c * 128;
  const int tid = threadIdx.x, tr = tid >> 4, tc = tid & 15;

  const float* Wg = W + (size_t)g * NN * NN;
  for (int e = tid; e < NN * NN; e += 512) {
    int k = e >> 7, i = e & 127;
    ldsW[k * TS + i] = Wg[e];
  }
  const float* xg = x + (size_t)g * NN * F0;
  const float* rg = rs + (size_t)g * NN * R;
  for (int e = tid; e < NN * NN; e += 512) {
    int k = e >> 7, dl = e & 127;
    int d = d0 + dl;
    float v = 0.f;
    if (d < DTOT) v = (d < F0) ? xg[k * F0 + d] : rg[k * R + (d - F0)] * rscale;
    ldsX[k * TS + dl] = v;
  }
  __syncthreads();

  float acc[4][8];
#pragma unroll
  for (int v = 0; v < 4; ++v)
#pragma unroll
    for (int u = 0; u < 8; ++u) acc[v][u] = 0.f;
  for (int k = 0; k < NN; ++k) {
    float4 w4 = *(const float4*)(ldsW + k * TS + 4 * tr);   // W symmetric rows
    float xv[8];
#pragma unroll
    for (int u = 0; u < 8; ++u) xv[u] = ldsX[k * TS + tc + 16 * u];
    float wvv[4] = {w4.x, w4.y, w4.z, w4.w};
#pragma unroll
    for (int v = 0; v < 4; ++v)
#pragma unroll
      for (int u = 0; u < 8; ++u) acc[v][u] = fmaf(wvv[v], xv[u], acc[v][u]);
  }
#pragma unroll
  for (int v = 0; v < 4; ++v)
#pragma unroll
    for (int u = 0; u < 8; ++u)
      acc[v][u] = ldsX[(4 * tr + v) * TS + tc + 16 * u] - acc[v][u];
  __syncthreads();

#pragma unroll
  for (int v = 0; v < 4; ++v)
#pragma unroll
    for (int u = 0; u < 8; ++u)
      ldsW[(tc + 16 * u) * TS + 4 * tr + v] = acc[v][u];
#pragma unroll
  for (int u = 0; u < 8; ++u) {
    float s = 0.f;
#pragma unroll
    for (int v = 0; v < 4; ++v) s += acc[v][u];
    ldsX[tr * EP + tc + 16 * u] = s;
  }
  __syncthreads();

  float gg[4][8];
#pragma unroll
  for (int v = 0; v < 4; ++v)
#pragma unroll
    for (int u = 0; u < 8; ++u) gg[v][u] = 0.f;
  for (int dl = 0; dl < NN; ++dl) {
    float4 a4v = *(const float4*)(ldsW + dl * TS + 4 * tr);
    float bv[8];
#pragma unroll
    for (int u = 0; u < 8; ++u) bv[u] = ldsW[dl * TS + tc + 16 * u];
    float av[4] = {a4v.x, a4v.y, a4v.z, a4v.w};
#pragma unroll
    for (int v = 0; v < 4; ++v)
#pragma unroll
      for (int u = 0; u < 8; ++u) gg[v][u] = fmaf(av[v], bv[u], gg[v][u]);
  }
  float* Gg = G + (size_t)g * NN * NN;
#pragma unroll
  for (int v = 0; v < 4; ++v)
#pragma unroll
    for (int u = 0; u < 8; ++u)
      atomicAdd(&Gg[(4 * tr + v) * NN + tc + 16 * u], gg[v][u]);

  if (tid < 128) {
    int d = d0 + tid;
    if (d < DTOT) {
      float s = 0.f;
      for (int tt = 0; tt < 32; ++tt) s += ldsX[tt * EP + tid];
      emb[(size_t)g * 1152 + d] = s * (1.f / 128.f);
    }
  }
}

// ---------------------------------------------------------------------------
// K45 (fused): blocks 0..63 = k4 (sp terms from G); 64..127 = k5a (cdist)
// ---------------------------------------------------------------------------
__global__ __launch_bounds__(256) void k45_fused(
    const float* __restrict__ G, double* __restrict__ spt,
    const float* __restrict__ emb, float* __restrict__ Dm, int DTOT) {
  __shared__ float inr[NN];
  __shared__ double red[4];
  const int bid = blockIdx.x, tid = threadIdx.x;
  if (bid < 64) {
    const int g = bid;
    const float* Gg = G + (size_t)g * NN * NN;
    if (tid < NN) {
      float n = sqrtf(fmaxf(Gg[tid * NN + tid], 0.f));
      inr[tid] = 1.f / fmaxf(n, 1e-12f);
    }
    __syncthreads();
    double s = 0.0;
    for (int e = tid; e < NN * NN; e += 256) {
      int i = e >> 7, j = e & 127;
      s += (double)(fabsf(Gg[e]) * inr[i] * inr[j]);
    }
    for (int off = 32; off; off >>= 1) s += __shfl_down(s, off);
    int wave = tid >> 6, lane = tid & 63;
    if (lane == 0) red[wave] = s;
    __syncthreads();
    if (tid == 0) spt[g] = -(red[0] + red[1] + red[2] + red[3]) / (double)(NN * NN);
  } else {
    const int i = bid - 64;
    const int wv = tid >> 6, l = tid & 63;
    float ei[18];
#pragma unroll
    for (int s = 0; s < 18; ++s) {
      int d = l + 64 * s;
      ei[s] = (d < DTOT) ? emb[(size_t)i * 1152 + d] : 0.f;
    }
    for (int jj = 0; jj < 16; ++jj) {
      int j = 4 * jj + wv;
      float acc = 0.f;
#pragma unroll
      for (int s = 0; s < 18; ++s) {
        int d = l + 64 * s;
        if (d < DTOT) {
          float df = ei[s] - emb[(size_t)j * 1152 + d];
          acc = fmaf(df, df, acc);
        }
      }
      for (int off = 32; off; off >>= 1) acc += __shfl_down(acc, off);
      if (l == 0) Dm[i * 64 + j] = (acc > 0.f) ? sqrtf(acc) : 0.f;
    }
  }
}

// ---------------------------------------------------------------------------
// K5b: final scalar (single wave)
// ---------------------------------------------------------------------------
__global__ __launch_bounds__(64) void k5b_final(
    const float* __restrict__ Dm, const double* __restrict__ spt,
    const float* __restrict__ C, int NF,
    const int* __restrict__ ncls, float* __restrict__ out) {
  const int lane = threadIdx.x;
  const int nc = ncls[0];
  double spf = spt[lane] * exp(-((double)(64 - lane)) * log(64.0));
  for (int off = 32; off; off >>= 1) spf += __shfl_down(spf, off);

  double hl1 = 0.0, hl2 = 0.0;
  const double beta = 1.0 / (double)nc + 1e-13;
  for (int cc = 0; cc < nc; ++cc) {
    bool ip = (lane % nc) == cc;
    double ps = 0.0, ns = 0.0;
    for (int j = 0; j < 64; ++j) {
      double dv = (double)Dm[lane * 64 + j];
      bool jp = (j % nc) == cc;
      if (ip && jp) ps += dv;
      if (!ip && !jp) ns += dv;
    }
    for (int off = 32; off; off >>= 1) {
      ps += __shfl_down(ps, off);
      ns += __shfl_down(ns, off);
    }
    int npos = 0;
    for (int q = 0; q < 64; ++q) if (q % nc == cc) npos++;
    int nneg = 64 - npos;
    hl2 += ps / ((double)npos * (double)npos);
    hl1 += -(ns / ((double)nneg * (double)nneg)) / beta;
  }
  if (lane == 0) {
    double l1 = 0.0, l2 = 0.0;
    for (int q = 0; q < NF; ++q) { double cv = (double)C[q]; l1 += fabs(cv); l2 += cv * cv; }
    l2 = sqrt(l2); if (l2 < 1e-12) l2 = 1e-12;
    double dims = sqrt((double)NF);
    double sc = (dims - l1 / l2) / (dims - 1.0);
    out[0] = (float)(sc + hl2 + hl1 + spf);
  }
}

// ---------------------------------------------------------------------------
extern "C" void kernel_launch(void* const* d_in, const int* in_sizes, int n_in,
                              void* d_out, int out_size, void* d_ws, size_t ws_size,
                              hipStream_t stream) {
  (void)n_in; (void)out_size; (void)ws_size;
  const float* x    = (const float*)d_in[0];
  const float* rs   = (const float*)d_in[1];
  const float* C    = (const float*)d_in[2];
  const int*   esrc = (const int*)d_in[3];
  const int*   edst = (const int*)d_in[4];
  const int*   ncls = (const int*)d_in[5];
  float* out = (float*)d_out;

  const int F0   = in_sizes[0] / (64 * 128);
  const int R    = in_sizes[1] / (64 * 128);
  const int NF   = in_sizes[2];
  const int E    = in_sizes[3] / 64;
  const int DTOT = F0 + R;
  const int NCH  = (DTOT + 127) / 128;
  const float rscale = (float)(1.0 / sqrt((double)R));

  char* ws = (char*)d_ws;
  size_t off = 0;
  float*  L    = (float*)(ws + off);  off += (size_t)64 * NN * NN * 4;
  float*  W    = (float*)(ws + off);  off += (size_t)64 * NN * NN * 4;
  float*  G    = (float*)(ws + off);  off += (size_t)64 * NN * NN * 4;
  double* L2d  = (double*)(ws + off); off += (size_t)64 * NN * NN * 8;
  double* L3d  = (double*)(ws + off); off += (size_t)64 * NN * NN * 8;
  double* L4d  = (double*)(ws + off); off += (size_t)64 * NN * NN * 8;
  float*  emb  = (float*)(ws + off);  off += (size_t)64 * 1152 * 4;
  double* spt  = (double*)(ws + off); off += (size_t)64 * 8;
  float*  Dm   = (float*)(ws + off);  off += (size_t)64 * 64 * 4;

  // W and G are contiguous: one memset covers both
  hipMemsetAsync(W, 0, (size_t)2 * 64 * NN * NN * 4, stream);

  const int lds1 = (NN * SM + NN) * 4;             // 66560
  const int ldsp = NN * SD * 8;                    // 133120 (f64 staging)
  const int lds2 = 2 * 16 * RS * 8 + 8 * 16 * SS * 8 + 2 * 16 * SS * 8;  // 55552
  const int lds3 = NN * TS * 4 * 2;                // 135168
  hipFuncSetAttribute((const void*)k1_lap,    hipFuncAttributeMaxDynamicSharedMemorySize, lds1);
  hipFuncSetAttribute((const void*)kpow2,     hipFuncAttributeMaxDynamicSharedMemorySize, ldsp);
  hipFuncSetAttribute((const void*)kpow34,    hipFuncAttributeMaxDynamicSharedMemorySize, ldsp);
  hipFuncSetAttribute((const void*)k2_filter, hipFuncAttributeMaxDynamicSharedMemorySize, lds2);
  hipFuncSetAttribute((const void*)k3_fused,  hipFuncAttributeMaxDynamicSharedMemorySize, lds3);

  k1_lap<<<64, 256, lds1, stream>>>(esrc, edst, E, L);
  kpow2<<<256, 512, ldsp, stream>>>(L, L2d);
  kpow34<<<256, 512, ldsp, stream>>>(L, L2d, L3d, L4d);
  k2_filter<<<64 * NF, 512, lds2, stream>>>(L, L2d, L3d, L4d, C, NF, W);
  k3_fused<<<64 * NCH, 512, lds3, stream>>>(x, rs, W, G, emb, F0, R, DTOT, NCH, rscale);
  k45_fused<<<128, 256, 0, stream>>>(G, spt, emb, Dm, DTOT);
  k5b_final<<<1, 64, 0, stream>>>(Dm, spt, C, NF, ncls, out);
}

// Round 3
// 601.769 us; speedup vs baseline: 1.6053x; 1.6053x over previous
//
#include <hip/hip_runtime.h>
#include <math.h>

#define NN 128
#define SM 129   // padded LDS stride for 128-wide f32 tiles
#define TS 132   // k3 tile stride (16B-aligned rows -> float4 LDS loads)
#define RS 132   // row-panel stride (doubles)
#define SS 17    // per-wave scratch stride (doubles)
#define SD 130   // padded LDS stride (doubles) for f64 matrix staging
#define EP 132   // emb-partial stride (floats)

typedef double d4 __attribute__((ext_vector_type(4)));

// ---------------------------------------------------------------------------
// K1 (R17): build symmetric-normalized Laplacian per graph (f32) only.
// ---------------------------------------------------------------------------
__global__ __launch_bounds__(256) void k1_lap(
    const int* __restrict__ src, const int* __restrict__ dst,
    int E, float* __restrict__ Lout) {
  extern __shared__ float sm1[];            // A[128*129] + dinv[128]
  float* A    = sm1;
  float* dinv = sm1 + NN * SM;
  const int g   = blockIdx.x;
  const int tid = threadIdx.x;

  for (int e = tid; e < NN * NN; e += 256) {
    int i = e >> 7, j = e & 127;
    A[i * SM + j] = 0.f;
  }
  __syncthreads();
  const int* s = src + (size_t)g * E;
  const int* d = dst + (size_t)g * E;
  for (int e = tid; e < E; e += 256) {
    int a = s[e], b = d[e];
    A[a * SM + b] = 1.f;     // benign races: all write 1.0
    A[b * SM + a] = 1.f;
  }
  __syncthreads();
  if (tid < NN) {
    float acc = 0.f;
    for (int j = 0; j < NN; ++j) acc += A[tid * SM + j];
    dinv[tid] = (acc > 0.f) ? (float)(1.0 / sqrt((double)acc)) : 0.f;
  }
  __syncthreads();
  float* Lg = Lout + (size_t)g * NN * NN;
  for (int e = tid; e < NN * NN; e += 256) {
    int i = e >> 7, j = e & 127;
    Lg[e] = ((i == j) ? 1.f : 0.f) - dinv[i] * dinv[j] * A[i * SM + j];
  }
}

// ---------------------------------------------------------------------------
// KPOW2 (R17): L2 = L @ L, 256 blocks (g = bid>>2, quarter q = bid&3 =
// 32-row band). B = L staged f64 in LDS; wave w: 16-row band q*32+16*(w&1),
// cb pair 2*(w>>1). Full-machine version of the old half-idle kernel.
// ---------------------------------------------------------------------------
__global__ __launch_bounds__(512, 1) void kpow2(
    const float* __restrict__ L, double* __restrict__ L2) {
  extern __shared__ double Bs[];            // 128 x 130 f64
  const int bid = blockIdx.x;
  const int g = bid >> 2, q = bid & 3;
  const int tid = threadIdx.x;
  const int wv = tid >> 6, ln = tid & 63;
  const int m  = ln & 15, kq = ln >> 4;
  const int rb = 32 * q + 16 * (wv & 1);    // row-band base
  const int cb0 = 2 * (wv >> 1);            // 2 col tiles

  int rIdx[4], cIdx[4];
  {
    d4 z = {0.0, 0.0, 0.0, 0.0};
    d4 pr = __builtin_amdgcn_mfma_f64_16x16x4f64((double)m, 1.0, z, 0, 0, 0);
    d4 pc = __builtin_amdgcn_mfma_f64_16x16x4f64(1.0, (double)m, z, 0, 0, 0);
#pragma unroll
    for (int r = 0; r < 4; ++r) {
      rIdx[r] = ((int)(pr[r] * 0.25 + 0.5)) & 15;
      cIdx[r] = ((int)(pc[r] * 0.25 + 0.5)) & 15;
    }
  }

  const float* Lg = L + (size_t)g * NN * NN;
  for (int e = tid; e < NN * NN; e += 512) {
    int i = e >> 7, j = e & 127;
    Bs[i * SD + j] = (double)Lg[e];
  }
  __syncthreads();

  d4 acc[2];
#pragma unroll
  for (int c = 0; c < 2; ++c) {
    acc[c][0] = 0.0; acc[c][1] = 0.0; acc[c][2] = 0.0; acc[c][3] = 0.0;
  }
  for (int kc = 0; kc < 32; ++kc) {
    double a = Bs[(rb + m) * SD + 4 * kc + kq];
#pragma unroll
    for (int c = 0; c < 2; ++c) {
      double b = Bs[(4 * kc + kq) * SD + 16 * (cb0 + c) + m];
      acc[c] = __builtin_amdgcn_mfma_f64_16x16x4f64(a, b, acc[c], 0, 0, 0);
    }
  }
  double* out = L2 + (size_t)g * NN * NN;
#pragma unroll
  for (int c = 0; c < 2; ++c)
#pragma unroll
    for (int r = 0; r < 4; ++r)
      out[(rb + rIdx[r]) * NN + 16 * (cb0 + c) + cIdx[r]] = acc[c][r];
}

// ---------------------------------------------------------------------------
// KPOW34 (R17): 256 blocks = g(6b) x half(1b) x job(1b).
// job 0: L3 = L2 @ L ; job 1: L4 = L2 @ L2. Each block: 64-row half-band.
// Wave w: band 64h + 16*(w&3), cb quad 4*(w>>2). B staged f64 in LDS;
// A rows read from global L2 (L2/L3-cached).
// ---------------------------------------------------------------------------
__global__ __launch_bounds__(512, 1) void kpow34(
    const float* __restrict__ L, const double* __restrict__ L2,
    double* __restrict__ L3, double* __restrict__ L4) {
  extern __shared__ double Bs[];            // 128 x 130 f64
  const int bid = blockIdx.x;
  const int g = bid >> 2, h = (bid >> 1) & 1, job = bid & 1;
  const int tid = threadIdx.x;
  const int wv = tid >> 6, ln = tid & 63;
  const int m  = ln & 15, kq = ln >> 4;
  const int rb = 64 * h + 16 * (wv & 3);
  const int cb0 = 4 * (wv >> 2);

  int rIdx[4], cIdx[4];
  {
    d4 z = {0.0, 0.0, 0.0, 0.0};
    d4 pr = __builtin_amdgcn_mfma_f64_16x16x4f64((double)m, 1.0, z, 0, 0, 0);
    d4 pc = __builtin_amdgcn_mfma_f64_16x16x4f64(1.0, (double)m, z, 0, 0, 0);
#pragma unroll
    for (int r = 0; r < 4; ++r) {
      rIdx[r] = ((int)(pr[r] * 0.25 + 0.5)) & 15;
      cIdx[r] = ((int)(pc[r] * 0.25 + 0.5)) & 15;
    }
  }

  const float*  Lg  = L  + (size_t)g * NN * NN;
  const double* L2g = L2 + (size_t)g * NN * NN;
  if (job == 0) {
    for (int e = tid; e < NN * NN; e += 512) {
      int i = e >> 7, j = e & 127;
      Bs[i * SD + j] = (double)Lg[e];
    }
  } else {
    for (int e = tid; e < NN * NN; e += 512) {
      int i = e >> 7, j = e & 127;
      Bs[i * SD + j] = L2g[e];
    }
  }
  __syncthreads();

  d4 acc[4];
#pragma unroll
  for (int c = 0; c < 4; ++c) {
    acc[c][0] = 0.0; acc[c][1] = 0.0; acc[c][2] = 0.0; acc[c][3] = 0.0;
  }
  for (int kc = 0; kc < 32; ++kc) {
    double a = L2g[(rb + m) * NN + 4 * kc + kq];
#pragma unroll
    for (int c = 0; c < 4; ++c) {
      double b = Bs[(4 * kc + kq) * SD + 16 * (cb0 + c) + m];
      acc[c] = __builtin_amdgcn_mfma_f64_16x16x4f64(a, b, acc[c], 0, 0, 0);
    }
  }
  double* out = (job == 0 ? L3 : L4) + (size_t)g * NN * NN;
#pragma unroll
  for (int c = 0; c < 4; ++c)
#pragma unroll
    for (int r = 0; r < 4; ++r)
      out[(rb + rIdx[r]) * NN + 16 * (cb0 + c) + cIdx[r]] = acc[c][r];
}

// ---------------------------------------------------------------------------
// K2 (R14 exact, frozen): algebraic assembly + blocked GJ with serial-Pi.
// 268us stable; MFMA-busy ~73us (GJ floor), VALU 13%, rest barrier stall.
// NOTE: register budget at __launch_bounds__(512,4) is exactly full
// (64 arch VGPR + 64 AGPR = 128). R18/R19 showed ANY restructuring of the
// pivot/staging regions triggers catastrophic scratch spill (800MB+ fetch).
// Do not modify without changing the algorithm.
// ---------------------------------------------------------------------------
__global__ __launch_bounds__(512, 4) void k2_filter(
    const float* __restrict__ L, const double* __restrict__ L2,
    const double* __restrict__ L3, const double* __restrict__ L4,
    const float* __restrict__ C, int NF, float* __restrict__ W) {
  extern __shared__ char smraw[];
  double* Rp  = (double*)smraw;                      // row panel 16x132
  double* Scd = (double*)(smraw + 16 * RS * 8);      // 8 wave scratches 16x17
  double* Pv  = (double*)(smraw + 16 * RS * 8 + 8 * 16 * SS * 8); // Pi 16x17

  const int bid = blockIdx.x;
  const int g = bid / NF, f = bid % NF;
  const int tid = threadIdx.x;
  const int wv = tid >> 6, ln = tid & 63;
  const int m  = ln & 15, kq = ln >> 4;
  double* S = Scd + wv * 16 * SS;

  double csum = 0.0;
  for (int q = 0; q < NF; ++q) { double c = (double)C[q]; csum += c * c; }
  double cn = sqrt(csum); if (cn < 1e-12) cn = 1e-12;
  const double a4 = 6.25e-6;                         // (STEP/2)^4
  const double coef = 1.4142135623730951 * a4 * ((double)C[f] / cn);
  const float  bf = (float)((double)f * 0.1);
  const double bb = (double)bf;
  const double c3 = -4.0 * bb;
  const double c2 = 6.0 * bb * bb;
  const double c1 = -4.0 * bb * bb * bb;
  const double c0 = bb * bb * bb * bb + a4;

  int rIdx[4], cIdx[4];
  {
    d4 z = {0.0, 0.0, 0.0, 0.0};
    d4 pr = __builtin_amdgcn_mfma_f64_16x16x4f64((double)m, 1.0, z, 0, 0, 0);
    d4 pc = __builtin_amdgcn_mfma_f64_16x16x4f64(1.0, (double)m, z, 0, 0, 0);
#pragma unroll
    for (int r = 0; r < 4; ++r) {
      rIdx[r] = ((int)(pr[r] * 0.25 + 0.5)) & 15;
      cIdx[r] = ((int)(pc[r] * 0.25 + 0.5)) & 15;
    }
  }

  // phase A: assemble T (D-layout) from the power matrices -- pure n^2
  const float*  Lg  = L  + (size_t)g * NN * NN;
  const double* L2g = L2 + (size_t)g * NN * NN;
  const double* L3g = L3 + (size_t)g * NN * NN;
  const double* L4g = L4 + (size_t)g * NN * NN;
  d4 T[8];
#pragma unroll
  for (int cb = 0; cb < 8; ++cb)
#pragma unroll
    for (int r = 0; r < 4; ++r) {
      int i = 16 * wv + rIdx[r], j = 16 * cb + cIdx[r];
      int idx = i * NN + j;
      double v = L4g[idx];
      v = fma(c3, L3g[idx], v);
      v = fma(c2, L2g[idx], v);
      v = fma(c1, (double)Lg[idx], v);
      if (i == j) v += c0;
      T[cb][r] = v;
    }

  // phase 4: blocked GJ, 8 steps, 3 block-barriers each, NOT unrolled
#pragma unroll 1
  for (int t = 0; t < 8; ++t) {
    if (wv == t) {
#pragma unroll
      for (int cb = 0; cb < 8; ++cb)
#pragma unroll
        for (int r = 0; r < 4; ++r)
          Rp[rIdx[r] * RS + 16 * cb + cIdx[r]] = T[cb][r];
    }
    __syncthreads();                                 // B1 (Rp visible)

    if (wv == t) {
      double sr[4];
#pragma unroll
      for (int r = 0; r < 4; ++r) sr[r] = Rp[(4 * r + kq) * RS + 16 * t + m];
#pragma unroll
      for (int k = 0; k < 16; ++k) {
        const int kr = k >> 2, kl = k & 3;
        double pv   = __shfl(sr[kr], 16 * kl + k);
        double rowv = __shfl(sr[kr], 16 * kl + m);
        double cv[4];
#pragma unroll
        for (int r = 0; r < 4; ++r) cv[r] = __shfl(sr[r], 16 * kq + k);
        double dp = 1.0 / pv;
#pragma unroll
        for (int r = 0; r < 4; ++r) {
          int i = 4 * r + kq;
          double nv;
          if (i == k)      nv = (m == k) ? dp : rowv * dp;
          else if (m == k) nv = -cv[r] * dp;
          else             nv = fma(-(cv[r] * dp), rowv, sr[r]);
          sr[r] = nv;
        }
      }
#pragma unroll
      for (int r = 0; r < 4; ++r) Pv[(4 * r + kq) * SS + m] = sr[r];
    }
    __syncthreads();                                 // B2 (Pi visible)

#pragma unroll
    for (int cb = 0; cb < 8; ++cb) {
      if (cb != t) continue;
      if (wv == t) {
#pragma unroll
        for (int r = 0; r < 4; ++r) T[cb][r] = Pv[rIdx[r] * SS + cIdx[r]];
      } else {
#pragma unroll
        for (int r = 0; r < 4; ++r) S[rIdx[r] * SS + cIdx[r]] = T[cb][r];
        __builtin_amdgcn_wave_barrier();
        d4 ncv = {0.0, 0.0, 0.0, 0.0};
#pragma unroll
        for (int kc = 0; kc < 4; ++kc) {
          double a = S[m * SS + 4 * kc + kq];
          double b = -Pv[(4 * kc + kq) * SS + m];
          ncv = __builtin_amdgcn_mfma_f64_16x16x4f64(a, b, ncv, 0, 0, 0);
        }
        T[cb] = ncv;
        __builtin_amdgcn_wave_barrier();
#pragma unroll
        for (int r = 0; r < 4; ++r) S[rIdx[r] * SS + cIdx[r]] = T[cb][r];
      }
    }
    __builtin_amdgcn_wave_barrier();

    const double* asrc = (wv == t) ? Pv : S;
#pragma unroll
    for (int cb = 0; cb < 8; ++cb) {
      if (cb == t) continue;
      d4 acc;
      if (wv == t) { acc[0] = 0.0; acc[1] = 0.0; acc[2] = 0.0; acc[3] = 0.0; }
      else         { acc = T[cb]; }
#pragma unroll
      for (int kc = 0; kc < 4; ++kc) {
        double a = asrc[m * SS + 4 * kc + kq];
        double b = Rp[(4 * kc + kq) * RS + 16 * cb + m];
        acc = __builtin_amdgcn_mfma_f64_16x16x4f64(a, b, acc, 0, 0, 0);
      }
      T[cb] = acc;
    }
    __syncthreads();                                 // B3 (Rp/Pv reads done)
  }

  // phase 5: W += coef * K^{-1}
  float* Wg = W + (size_t)g * NN * NN;
#pragma unroll
  for (int cb = 0; cb < 8; ++cb)
#pragma unroll
    for (int r = 0; r < 4; ++r)
      atomicAdd(&Wg[(16 * wv + rIdx[r]) * NN + 16 * cb + cIdx[r]],
                (float)(coef * T[cb][r]));
}

// ---------------------------------------------------------------------------
// K3 (R20): single-LDS-buffer version. W is NOT staged (rows read directly
// from global with a 1-step register prefetch; W is 64KB/graph, L2-resident,
// reused by NCH channel blocks). yT overwrites the dead X buffer in place;
// emb partials accumulate via LDS atomics. LDS 135KB -> 68.6KB => 2
// blocks/CU and all 320 blocks co-resident in one scheduling round.
// ---------------------------------------------------------------------------
__global__ __launch_bounds__(512, 4) void k3_fused(
    const float* __restrict__ x, const float* __restrict__ rs,
    const float* __restrict__ W, float* __restrict__ G,
    float* __restrict__ emb, int F0, int R, int DTOT, int NCH,
    float rscale) {
  extern __shared__ float sm3[];
  float* ldsX = sm3;                 // 128*132 f32: X, later yT (in place)
  float* embA = sm3 + NN * TS;       // 128 f32 emb accumulator
  const int bid = blockIdx.x;
  const int g = bid / NCH;
  const int c = bid % NCH;
  const int d0 = c * 128;
  const int tid = threadIdx.x, tr = tid >> 4, tc = tid & 15;

  const float* xg = x + (size_t)g * NN * F0;
  const float* rg = rs + (size_t)g * NN * R;
  for (int e = tid; e < NN * NN; e += 512) {
    int k = e >> 7, dl = e & 127;
    int d = d0 + dl;
    float v = 0.f;
    if (d < DTOT) v = (d < F0) ? xg[k * F0 + d] : rg[k * R + (d - F0)] * rscale;
    ldsX[k * TS + dl] = v;
  }
  if (tid < NN) embA[tid] = 0.f;
  __syncthreads();

  // first gemm: y = X - W@X, W rows streamed from global (L2-hot)
  const float* Wg = W + (size_t)g * NN * NN;
  float acc[4][8];
#pragma unroll
  for (int v = 0; v < 4; ++v)
#pragma unroll
    for (int u = 0; u < 8; ++u) acc[v][u] = 0.f;
  float4 w4 = *(const float4*)(Wg + 4 * tr);
  for (int k = 0; k < NN; ++k) {
    float4 w4n;
    if (k < NN - 1) w4n = *(const float4*)(Wg + (k + 1) * NN + 4 * tr);
    float xv[8];
#pragma unroll
    for (int u = 0; u < 8; ++u) xv[u] = ldsX[k * TS + tc + 16 * u];
    float wvv[4] = {w4.x, w4.y, w4.z, w4.w};
#pragma unroll
    for (int v = 0; v < 4; ++v)
#pragma unroll
      for (int u = 0; u < 8; ++u) acc[v][u] = fmaf(wvv[v], xv[u], acc[v][u]);
    w4 = w4n;
  }
#pragma unroll
  for (int v = 0; v < 4; ++v)
#pragma unroll
    for (int u = 0; u < 8; ++u)
      acc[v][u] = ldsX[(4 * tr + v) * TS + tc + 16 * u] - acc[v][u];

  // emb partials: column sums of y via LDS atomics
#pragma unroll
  for (int u = 0; u < 8; ++u) {
    float s = acc[0][u] + acc[1][u] + acc[2][u] + acc[3][u];
    atomicAdd(&embA[tc + 16 * u], s);
  }
  __syncthreads();                 // all X reads + embA adds complete

  // write yT in place over the dead X buffer
#pragma unroll
  for (int v = 0; v < 4; ++v)
#pragma unroll
    for (int u = 0; u < 8; ++u)
      ldsX[(tc + 16 * u) * TS + 4 * tr + v] = acc[v][u];
  __syncthreads();

  // emb write (fire-and-forget, overlaps second gemm)
  if (tid < 128) {
    int d = d0 + tid;
    if (d < DTOT) emb[(size_t)g * 1152 + d] = embA[tid] * (1.f / 128.f);
  }

  // second gemm: G += y @ y^T (chunk contribution)
  float gg[4][8];
#pragma unroll
  for (int v = 0; v < 4; ++v)
#pragma unroll
    for (int u = 0; u < 8; ++u) gg[v][u] = 0.f;
  for (int dl = 0; dl < NN; ++dl) {
    float4 a4v = *(const float4*)(ldsX + dl * TS + 4 * tr);
    float bv[8];
#pragma unroll
    for (int u = 0; u < 8; ++u) bv[u] = ldsX[dl * TS + tc + 16 * u];
    float av[4] = {a4v.x, a4v.y, a4v.z, a4v.w};
#pragma unroll
    for (int v = 0; v < 4; ++v)
#pragma unroll
      for (int u = 0; u < 8; ++u) gg[v][u] = fmaf(av[v], bv[u], gg[v][u]);
  }
  float* Gg = G + (size_t)g * NN * NN;
#pragma unroll
  for (int v = 0; v < 4; ++v)
#pragma unroll
    for (int u = 0; u < 8; ++u)
      atomicAdd(&Gg[(4 * tr + v) * NN + tc + 16 * u], gg[v][u]);
}

// ---------------------------------------------------------------------------
// K45 (fused): blocks 0..63 = k4 (sp terms from G); 64..127 = k5a (cdist)
// ---------------------------------------------------------------------------
__global__ __launch_bounds__(256) void k45_fused(
    const float* __restrict__ G, double* __restrict__ spt,
    const float* __restrict__ emb, float* __restrict__ Dm, int DTOT) {
  __shared__ float inr[NN];
  __shared__ double red[4];
  const int bid = blockIdx.x, tid = threadIdx.x;
  if (bid < 64) {
    const int g = bid;
    const float* Gg = G + (size_t)g * NN * NN;
    if (tid < NN) {
      float n = sqrtf(fmaxf(Gg[tid * NN + tid], 0.f));
      inr[tid] = 1.f / fmaxf(n, 1e-12f);
    }
    __syncthreads();
    double s = 0.0;
    for (int e = tid; e < NN * NN; e += 256) {
      int i = e >> 7, j = e & 127;
      s += (double)(fabsf(Gg[e]) * inr[i] * inr[j]);
    }
    for (int off = 32; off; off >>= 1) s += __shfl_down(s, off);
    int wave = tid >> 6, lane = tid & 63;
    if (lane == 0) red[wave] = s;
    __syncthreads();
    if (tid == 0) spt[g] = -(red[0] + red[1] + red[2] + red[3]) / (double)(NN * NN);
  } else {
    const int i = bid - 64;
    const int wv = tid >> 6, l = tid & 63;
    float ei[18];
#pragma unroll
    for (int s = 0; s < 18; ++s) {
      int d = l + 64 * s;
      ei[s] = (d < DTOT) ? emb[(size_t)i * 1152 + d] : 0.f;
    }
    for (int jj = 0; jj < 16; ++jj) {
      int j = 4 * jj + wv;
      float acc = 0.f;
#pragma unroll
      for (int s = 0; s < 18; ++s) {
        int d = l + 64 * s;
        if (d < DTOT) {
          float df = ei[s] - emb[(size_t)j * 1152 + d];
          acc = fmaf(df, df, acc);
        }
      }
      for (int off = 32; off; off >>= 1) acc += __shfl_down(acc, off);
      if (l == 0) Dm[i * 64 + j] = (acc > 0.f) ? sqrtf(acc) : 0.f;
    }
  }
}

// ---------------------------------------------------------------------------
// K5b: final scalar (single wave)
// ---------------------------------------------------------------------------
__global__ __launch_bounds__(64) void k5b_final(
    const float* __restrict__ Dm, const double* __restrict__ spt,
    const float* __restrict__ C, int NF,
    const int* __restrict__ ncls, float* __restrict__ out) {
  const int lane = threadIdx.x;
  const int nc = ncls[0];
  double spf = spt[lane] * exp(-((double)(64 - lane)) * log(64.0));
  for (int off = 32; off; off >>= 1) spf += __shfl_down(spf, off);

  double hl1 = 0.0, hl2 = 0.0;
  const double beta = 1.0 / (double)nc + 1e-13;
  for (int cc = 0; cc < nc; ++cc) {
    bool ip = (lane % nc) == cc;
    double ps = 0.0, ns = 0.0;
    for (int j = 0; j < 64; ++j) {
      double dv = (double)Dm[lane * 64 + j];
      bool jp = (j % nc) == cc;
      if (ip && jp) ps += dv;
      if (!ip && !jp) ns += dv;
    }
    for (int off = 32; off; off >>= 1) {
      ps += __shfl_down(ps, off);
      ns += __shfl_down(ns, off);
    }
    int npos = 0;
    for (int q = 0; q < 64; ++q) if (q % nc == cc) npos++;
    int nneg = 64 - npos;
    hl2 += ps / ((double)npos * (double)npos);
    hl1 += -(ns / ((double)nneg * (double)nneg)) / beta;
  }
  if (lane == 0) {
    double l1 = 0.0, l2 = 0.0;
    for (int q = 0; q < NF; ++q) { double cv = (double)C[q]; l1 += fabs(cv); l2 += cv * cv; }
    l2 = sqrt(l2); if (l2 < 1e-12) l2 = 1e-12;
    double dims = sqrt((double)NF);
    double sc = (dims - l1 / l2) / (dims - 1.0);
    out[0] = (float)(sc + hl2 + hl1 + spf);
  }
}

// ---------------------------------------------------------------------------
extern "C" void kernel_launch(void* const* d_in, const int* in_sizes, int n_in,
                              void* d_out, int out_size, void* d_ws, size_t ws_size,
                              hipStream_t stream) {
  (void)n_in; (void)out_size; (void)ws_size;
  const float* x    = (const float*)d_in[0];
  const float* rs   = (const float*)d_in[1];
  const float* C    = (const float*)d_in[2];
  const int*   esrc = (const int*)d_in[3];
  const int*   edst = (const int*)d_in[4];
  const int*   ncls = (const int*)d_in[5];
  float* out = (float*)d_out;

  const int F0   = in_sizes[0] / (64 * 128);
  const int R    = in_sizes[1] / (64 * 128);
  const int NF   = in_sizes[2];
  const int E    = in_sizes[3] / 64;
  const int DTOT = F0 + R;
  const int NCH  = (DTOT + 127) / 128;
  const float rscale = (float)(1.0 / sqrt((double)R));

  char* ws = (char*)d_ws;
  size_t off = 0;
  float*  L    = (float*)(ws + off);  off += (size_t)64 * NN * NN * 4;
  float*  W    = (float*)(ws + off);  off += (size_t)64 * NN * NN * 4;
  float*  G    = (float*)(ws + off);  off += (size_t)64 * NN * NN * 4;
  double* L2d  = (double*)(ws + off); off += (size_t)64 * NN * NN * 8;
  double* L3d  = (double*)(ws + off); off += (size_t)64 * NN * NN * 8;
  double* L4d  = (double*)(ws + off); off += (size_t)64 * NN * NN * 8;
  float*  emb  = (float*)(ws + off);  off += (size_t)64 * 1152 * 4;
  double* spt  = (double*)(ws + off); off += (size_t)64 * 8;
  float*  Dm   = (float*)(ws + off);  off += (size_t)64 * 64 * 4;

  // W and G are contiguous: one memset covers both
  hipMemsetAsync(W, 0, (size_t)2 * 64 * NN * NN * 4, stream);

  const int lds1 = (NN * SM + NN) * 4;             // 66560
  const int ldsp = NN * SD * 8;                    // 133120 (f64 staging)
  const int lds2 = 16 * RS * 8 + 8 * 16 * SS * 8 + 16 * SS * 8;  // 36480
  const int lds3 = (NN * TS + NN) * 4;             // 68096 -> 2 blocks/CU
  hipFuncSetAttribute((const void*)k1_lap,    hipFuncAttributeMaxDynamicSharedMemorySize, lds1);
  hipFuncSetAttribute((const void*)kpow2,     hipFuncAttributeMaxDynamicSharedMemorySize, ldsp);
  hipFuncSetAttribute((const void*)kpow34,    hipFuncAttributeMaxDynamicSharedMemorySize, ldsp);
  hipFuncSetAttribute((const void*)k2_filter, hipFuncAttributeMaxDynamicSharedMemorySize, lds2);
  hipFuncSetAttribute((const void*)k3_fused,  hipFuncAttributeMaxDynamicSharedMemorySize, lds3);

  k1_lap<<<64, 256, lds1, stream>>>(esrc, edst, E, L);
  kpow2<<<256, 512, ldsp, stream>>>(L, L2d);
  kpow34<<<256, 512, ldsp, stream>>>(L, L2d, L3d, L4d);
  k2_filter<<<64 * NF, 512, lds2, stream>>>(L, L2d, L3d, L4d, C, NF, W);
  k3_fused<<<64 * NCH, 512, lds3, stream>>>(x, rs, W, G, emb, F0, R, DTOT, NCH, rscale);
  k45_fused<<<128, 256, 0, stream>>>(G, spt, emb, Dm, DTOT);
  k5b_final<<<1, 64, 0, stream>>>(Dm, spt, C, NF, ncls, out);
}